// Round 1
// baseline (81128.094 us; speedup 1.0000x reference)
//
#include <hip/hip_runtime.h>
#include <stdint.h>

// Problem constants
#define B_ 32
#define T_ 2048
#define D_ 512
#define N_ 512
#define NG 2048   // 4 gates * N

typedef _Float16 f16;
typedef _Float16 half2v __attribute__((ext_vector_type(2)));
typedef _Float16 half8  __attribute__((ext_vector_type(8)));
typedef float    float4v __attribute__((ext_vector_type(4)));

union U32H2 { unsigned u; half2v h; };

static __device__ __forceinline__ float fdot2(unsigned a, unsigned b, float c) {
#if __has_builtin(__builtin_amdgcn_fdot2)
    U32H2 ua; ua.u = a; U32H2 ub; ub.u = b;
    return __builtin_amdgcn_fdot2(ua.h, ub.h, c, false);
#else
    U32H2 ua; ua.u = a; U32H2 ub; ub.u = b;
    c += (float)ua.h[0] * (float)ub.h[0];
    c += (float)ua.h[1] * (float)ub.h[1];
    return c;
#endif
}

// ---------------- prep: cast x (f32) -> f16 ----------------
__global__ void prep_cast(const float* __restrict__ x, f16* __restrict__ x16) {
    long i = ((long)blockIdx.x * 256 + threadIdx.x) * 4;
    float4 v = *(const float4*)(x + i);
    union { f16 h[4]; uint2 u; } pk;
    pk.h[0] = (f16)v.x; pk.h[1] = (f16)v.y; pk.h[2] = (f16)v.z; pk.h[3] = (f16)v.w;
    *(uint2*)(x16 + i) = pk.u;
}

// ---------------- prep: transpose+cast weights, biases, zero flags ----------------
__global__ void prep_w(const float* __restrict__ Wi, const float* __restrict__ Ui,
                       const float* __restrict__ Wf, const float* __restrict__ Uf,
                       const float* __restrict__ Wg, const float* __restrict__ Ug,
                       const float* __restrict__ Wc, const float* __restrict__ Uc,
                       const float* __restrict__ Wo,
                       const float* __restrict__ bi, const float* __restrict__ bff,
                       const float* __restrict__ bg, const float* __restrict__ bc,
                       f16* __restrict__ wt, f16* __restrict__ ut,
                       f16* __restrict__ wot, float* __restrict__ bias,
                       unsigned* __restrict__ flags)
{
    const int y = blockIdx.y;
    const int e = blockIdx.x * 256 + threadIdx.x;   // 0..262143
    if (y < 4) {
        const float* src = (y == 0) ? Wi : (y == 1) ? Wf : (y == 2) ? Wg : Wc;
        int col = e >> 9, d = e & 511;
        wt[(long)y * 512 * 512 + e] = (f16)src[(long)d * 512 + col];   // wt[(g*512+col)][d]
    } else if (y < 8) {
        const float* src = (y == 4) ? Ui : (y == 5) ? Uf : (y == 6) ? Ug : Uc;
        int col = e >> 9, d = e & 511;
        ut[(long)(y - 4) * 512 * 512 + e] = (f16)src[(long)d * 512 + col];
    } else if (y == 8) {
        int col = e >> 9, d = e & 511;
        wot[e] = (f16)Wo[(long)d * 512 + col];
    } else {
        if (e < 2048) {
            const float* bsrc = (e < 512) ? bi : (e < 1024) ? bff : (e < 1536) ? bg : bc;
            bias[e] = bsrc[e & 511];
        } else if (e < 2048 + 1024) {
            flags[e - 2048] = 0u;   // 32 batches * stride 32
        }
    }
}

// ---------------- phase 1: xpre[b][t][2048] = x @ [Wi|Wf|Wg|Wc] + bias (f16 out) ----------------
__launch_bounds__(256)
__global__ void gemm_xw(const f16* __restrict__ A, const f16* __restrict__ Bt,
                        const float* __restrict__ bias, f16* __restrict__ C)
{
    __shared__ f16 sA[128 * 32];
    __shared__ f16 sB[128 * 32];
    const int tid = threadIdx.x;
    const int m0 = blockIdx.y * 128;
    const int n0 = blockIdx.x * 128;
    const int wave = tid >> 6, lane = tid & 63;
    const int wm = wave >> 1, wn = wave & 1;
    const int lrow = lane & 15, quad = lane >> 4;

    float4v acc[4][4];
#pragma unroll
    for (int i = 0; i < 4; i++)
#pragma unroll
        for (int j = 0; j < 4; j++) acc[i][j] = (float4v){0.f, 0.f, 0.f, 0.f};

    const int srow = tid >> 2;        // 0..63
    const int sk8 = (tid & 3) * 8;    // 0,8,16,24

    for (int k0 = 0; k0 < 512; k0 += 32) {
#pragma unroll
        for (int rr = 0; rr < 128; rr += 64) {
            const int row = rr + srow;
            *(uint4*)&sA[row * 32 + sk8] = *(const uint4*)&A[(long)(m0 + row) * 512 + k0 + sk8];
            *(uint4*)&sB[row * 32 + sk8] = *(const uint4*)&Bt[(long)(n0 + row) * 512 + k0 + sk8];
        }
        __syncthreads();
        half8 af[4], bf[4];
#pragma unroll
        for (int mi = 0; mi < 4; mi++)
            af[mi] = *(half8*)&sA[(wm * 64 + mi * 16 + lrow) * 32 + quad * 8];
#pragma unroll
        for (int ni = 0; ni < 4; ni++)
            bf[ni] = *(half8*)&sB[(wn * 64 + ni * 16 + lrow) * 32 + quad * 8];
#pragma unroll
        for (int mi = 0; mi < 4; mi++)
#pragma unroll
            for (int ni = 0; ni < 4; ni++)
                acc[mi][ni] = __builtin_amdgcn_mfma_f32_16x16x32_f16(af[mi], bf[ni], acc[mi][ni], 0, 0, 0);
        __syncthreads();
    }
#pragma unroll
    for (int mi = 0; mi < 4; mi++)
#pragma unroll
        for (int ni = 0; ni < 4; ni++)
#pragma unroll
            for (int r = 0; r < 4; r++) {
                int m = m0 + wm * 64 + mi * 16 + quad * 4 + r;
                int n = n0 + wn * 64 + ni * 16 + lrow;
                C[(long)m * NG + n] = (f16)(acc[mi][ni][r] + bias[n]);
            }
}

// ---------------- phase 3: out[b][t][n] = relu(hs @ Wo + bo) (f32 out, row remap) ----------------
__launch_bounds__(256)
__global__ void gemm_hw(const f16* __restrict__ A, const f16* __restrict__ Bt,
                        const float* __restrict__ bias, float* __restrict__ out)
{
    __shared__ f16 sA[128 * 32];
    __shared__ f16 sB[128 * 32];
    const int tid = threadIdx.x;
    const int m0 = blockIdx.y * 128;
    const int n0 = blockIdx.x * 128;
    const int wave = tid >> 6, lane = tid & 63;
    const int wm = wave >> 1, wn = wave & 1;
    const int lrow = lane & 15, quad = lane >> 4;

    float4v acc[4][4];
#pragma unroll
    for (int i = 0; i < 4; i++)
#pragma unroll
        for (int j = 0; j < 4; j++) acc[i][j] = (float4v){0.f, 0.f, 0.f, 0.f};

    const int srow = tid >> 2;
    const int sk8 = (tid & 3) * 8;

    for (int k0 = 0; k0 < 512; k0 += 32) {
#pragma unroll
        for (int rr = 0; rr < 128; rr += 64) {
            const int row = rr + srow;
            *(uint4*)&sA[row * 32 + sk8] = *(const uint4*)&A[(long)(m0 + row) * 512 + k0 + sk8];
            *(uint4*)&sB[row * 32 + sk8] = *(const uint4*)&Bt[(long)(n0 + row) * 512 + k0 + sk8];
        }
        __syncthreads();
        half8 af[4], bf[4];
#pragma unroll
        for (int mi = 0; mi < 4; mi++)
            af[mi] = *(half8*)&sA[(wm * 64 + mi * 16 + lrow) * 32 + quad * 8];
#pragma unroll
        for (int ni = 0; ni < 4; ni++)
            bf[ni] = *(half8*)&sB[(wn * 64 + ni * 16 + lrow) * 32 + quad * 8];
#pragma unroll
        for (int mi = 0; mi < 4; mi++)
#pragma unroll
            for (int ni = 0; ni < 4; ni++)
                acc[mi][ni] = __builtin_amdgcn_mfma_f32_16x16x32_f16(af[mi], bf[ni], acc[mi][ni], 0, 0, 0);
        __syncthreads();
    }
#pragma unroll
    for (int mi = 0; mi < 4; mi++)
#pragma unroll
        for (int ni = 0; ni < 4; ni++)
#pragma unroll
            for (int r = 0; r < 4; r++) {
                int m = m0 + wm * 64 + mi * 16 + quad * 4 + r;   // m = t*B + b
                int n = n0 + wn * 64 + ni * 16 + lrow;
                float v = acc[mi][ni][r] + bias[n];
                v = fmaxf(v, 0.f);
                int t = m >> 5, b = m & 31;
                out[(long)b * (T_ * (long)N_) + (long)t * N_ + n] = v;
            }
}

// ---------------- phase 2: the recurrence ----------------
// 32 groups (one per batch) x 8 blocks x 512 threads. Each thread holds half a
// U column (128 VGPRs of packed f16 pairs). One device-scope flag sync per step.
__launch_bounds__(512, 2)
__global__ void lstm_rec(const f16* __restrict__ Ut,    // [2048 cols][512 rows] f16
                         const f16* __restrict__ xpre,  // [B][T][2048] f16
                         f16* __restrict__ hglob,       // [2][32][512] f16 (double buffer)
                         f16* __restrict__ hs,          // [T][B][512] f16
                         unsigned* __restrict__ flags)  // [32 * 32] (stride 32)
{
    const int tid = threadIdx.x;
    const int bb = blockIdx.x & 31;   // batch
    const int s  = blockIdx.x >> 5;   // slice 0..7 (blocks of a group are 32 apart -> same XCD)
    const int c    = tid & 255;       // column within block: c = g*64 + e
    const int half = tid >> 8;        // which half of the 512-row column
    const int g = c >> 6, e = c & 63;
    const int gcol = g * 512 + s * 64 + e;   // global gate-column

    __shared__ uint4 hbuf4[64];       // h_{t-1} as 512 f16 (pairs)
    __shared__ float part[512];
    __shared__ float prelds[256];

    // Load U half-column into registers (statically indexed -> VGPRs)
    uint4 u[32];
    const uint4* Ub = (const uint4*)(Ut + (long)gcol * 512) + half * 32;
#pragma unroll
    for (int k = 0; k < 32; k++) u[k] = Ub[k];

    if (tid < 64) hbuf4[tid] = make_uint4(0u, 0u, 0u, 0u);  // h_{-1} = 0
    float cstate = 0.f;   // valid for tid<64: c-state of element n = s*64+tid
    __syncthreads();

    const f16* xp_base = xpre + (long)bb * T_ * NG + gcol;
    f16* hg0 = hglob + bb * 512;
    f16* hg1 = hglob + 32 * 512 + bb * 512;
    unsigned* flag = flags + bb * 32;

    for (int t = 0; t < T_; ++t) {
        float xpv = 0.f;
        if (tid < 256) xpv = (float)xp_base[(long)t * NG];  // independent of h; hides latency

        // dot: pre-activation partial for column gcol over this thread's half rows
        float a0 = 0.f, a1 = 0.f, a2 = 0.f, a3 = 0.f;
        const uint4* hb = hbuf4 + half * 32;
#pragma unroll
        for (int k = 0; k < 32; k++) {
            uint4 hv = hb[k];           // broadcast read (all lanes same addr)
            a0 = fdot2(hv.x, u[k].x, a0);
            a1 = fdot2(hv.y, u[k].y, a1);
            a2 = fdot2(hv.z, u[k].z, a2);
            a3 = fdot2(hv.w, u[k].w, a3);
        }
        part[half * 256 + c] = (a0 + a1) + (a2 + a3);
        __syncthreads();

        if (tid < 256) prelds[tid] = part[tid] + part[256 + tid] + xpv;
        __syncthreads();

        if (tid < 64) {
            float pi = prelds[tid];
            float pf = prelds[64 + tid];
            float pg = prelds[128 + tid];
            float pc = prelds[192 + tid];
            float gi = 1.f / (1.f + __expf(-pi));
            float gf = 1.f / (1.f + __expf(-pf));
            float gg = 1.f / (1.f + __expf(-pg));   // reference uses sigmoid for g
            float ct = tanhf(pc);
            cstate = gf * cstate + gi * ct;
            float h = gg * tanhf(cstate);
            f16 h16 = (f16)h;
            int n = s * 64 + tid;
            (( (t + 1) & 1 ) ? hg1 : hg0)[n] = h16;          // write buffer (t+1)&1
            hs[((long)t * B_ + bb) * 512 + n] = h16;
        }
        __syncthreads();

        if (tid == 0) {
            __threadfence();
            __hip_atomic_fetch_add(flag, 1u, __ATOMIC_RELEASE, __HIP_MEMORY_SCOPE_AGENT);
            const unsigned target = 8u * (unsigned)(t + 1);
            while (__hip_atomic_load(flag, __ATOMIC_ACQUIRE, __HIP_MEMORY_SCOPE_AGENT) < target)
                __builtin_amdgcn_s_sleep(1);
        }
        __syncthreads();
        __threadfence();   // acquire: invalidate caches before reading peers' h

        if (tid < 64) {
            const f16* src = ((t + 1) & 1) ? hg1 : hg0;
            hbuf4[tid] = *(const uint4*)&src[tid * 8];
        }
        __syncthreads();
    }
}

// ---------------- launch ----------------
extern "C" void kernel_launch(void* const* d_in, const int* in_sizes, int n_in,
                              void* d_out, int out_size, void* d_ws, size_t ws_size,
                              hipStream_t stream)
{
    const float* x  = (const float*)d_in[0];
    const float* Wi = (const float*)d_in[1];
    const float* Ui = (const float*)d_in[2];
    const float* Wf = (const float*)d_in[3];
    const float* Uf = (const float*)d_in[4];
    const float* Wg = (const float*)d_in[5];
    const float* Ug = (const float*)d_in[6];
    const float* Wc = (const float*)d_in[7];
    const float* Uc = (const float*)d_in[8];
    const float* Wo = (const float*)d_in[9];
    const float* bi = (const float*)d_in[10];
    const float* bf = (const float*)d_in[11];
    const float* bg = (const float*)d_in[12];
    const float* bc = (const float*)d_in[13];
    const float* bo = (const float*)d_in[14];

    char* ws = (char*)d_ws;
    f16*      x16   = (f16*)(ws + 0L);            // 64 MB
    f16*      xpre  = (f16*)(ws + 67108864L);     // 256 MB
    f16*      hs    = (f16*)(ws + 335544320L);    // 64 MB
    f16*      wt    = (f16*)(ws + 402653184L);    // 2 MB
    f16*      ut    = (f16*)(ws + 404750336L);    // 2 MB
    f16*      wot   = (f16*)(ws + 406847488L);    // 0.5 MB
    float*    bias  = (float*)(ws + 407371776L);  // 8 KB
    f16*      hg    = (f16*)(ws + 407379968L);    // 64 KB
    unsigned* flags = (unsigned*)(ws + 407445504L); // 4 KB

    prep_cast<<<dim3(32768), dim3(256), 0, stream>>>(x, x16);
    prep_w<<<dim3(1024, 10), dim3(256), 0, stream>>>(Wi, Ui, Wf, Uf, Wg, Ug, Wc, Uc, Wo,
                                                     bi, bf, bg, bc, wt, ut, wot, bias, flags);
    gemm_xw<<<dim3(16, 512), dim3(256), 0, stream>>>(x16, wt, bias, xpre);
    lstm_rec<<<dim3(256), dim3(512), 0, stream>>>(ut, xpre, hg, hs, flags);
    gemm_hw<<<dim3(4, 512), dim3(256), 0, stream>>>(hs, wot, bo, (float*)d_out);
}

// Round 2
// 6561.409 us; speedup vs baseline: 12.3644x; 12.3644x over previous
//
#include <hip/hip_runtime.h>
#include <stdint.h>

// Problem constants
#define B_ 32
#define T_ 2048
#define D_ 512
#define N_ 512
#define NG 2048   // 4 gates * N

typedef _Float16 f16;
typedef _Float16 half2v __attribute__((ext_vector_type(2)));
typedef _Float16 half8  __attribute__((ext_vector_type(8)));
typedef float    float4v __attribute__((ext_vector_type(4)));

union U32H2 { unsigned u; half2v h; };

static __device__ __forceinline__ float fdot2(unsigned a, unsigned b, float c) {
#if __has_builtin(__builtin_amdgcn_fdot2)
    U32H2 ua; ua.u = a; U32H2 ub; ub.u = b;
    return __builtin_amdgcn_fdot2(ua.h, ub.h, c, false);
#else
    U32H2 ua; ua.u = a; U32H2 ub; ub.u = b;
    c += (float)ua.h[0] * (float)ub.h[0];
    c += (float)ua.h[1] * (float)ub.h[1];
    return c;
#endif
}

// ---------------- prep: cast x (f32) -> f16 ----------------
__global__ void prep_cast(const float* __restrict__ x, f16* __restrict__ x16) {
    long i = ((long)blockIdx.x * 256 + threadIdx.x) * 4;
    float4 v = *(const float4*)(x + i);
    union { f16 h[4]; uint2 u; } pk;
    pk.h[0] = (f16)v.x; pk.h[1] = (f16)v.y; pk.h[2] = (f16)v.z; pk.h[3] = (f16)v.w;
    *(uint2*)(x16 + i) = pk.u;
}

// ---------------- prep: transpose+cast weights, biases, zero flags ----------------
__global__ void prep_w(const float* __restrict__ Wi, const float* __restrict__ Ui,
                       const float* __restrict__ Wf, const float* __restrict__ Uf,
                       const float* __restrict__ Wg, const float* __restrict__ Ug,
                       const float* __restrict__ Wc, const float* __restrict__ Uc,
                       const float* __restrict__ Wo,
                       const float* __restrict__ bi, const float* __restrict__ bff,
                       const float* __restrict__ bg, const float* __restrict__ bc,
                       f16* __restrict__ wt, f16* __restrict__ ut,
                       f16* __restrict__ wot, float* __restrict__ bias,
                       unsigned* __restrict__ flags)
{
    const int y = blockIdx.y;
    const int e = blockIdx.x * 256 + threadIdx.x;   // 0..262143
    if (y < 4) {
        const float* src = (y == 0) ? Wi : (y == 1) ? Wf : (y == 2) ? Wg : Wc;
        int col = e >> 9, d = e & 511;
        wt[(long)y * 512 * 512 + e] = (f16)src[(long)d * 512 + col];   // wt[(g*512+col)][d]
    } else if (y < 8) {
        const float* src = (y == 4) ? Ui : (y == 5) ? Uf : (y == 6) ? Ug : Uc;
        int col = e >> 9, d = e & 511;
        ut[(long)(y - 4) * 512 * 512 + e] = (f16)src[(long)d * 512 + col];
    } else if (y == 8) {
        int col = e >> 9, d = e & 511;
        wot[e] = (f16)Wo[(long)d * 512 + col];
    } else {
        if (e < 2048) {
            const float* bsrc = (e < 512) ? bi : (e < 1024) ? bff : (e < 1536) ? bg : bc;
            bias[e] = bsrc[e & 511];
        } else if (e < 2048 + 1024) {
            flags[e - 2048] = 0u;   // 32 batches * stride 32
        }
    }
}

// ---------------- phase 1: xpre[b][t][2048] = x @ [Wi|Wf|Wg|Wc] + bias (f16 out) ----------------
__launch_bounds__(256)
__global__ void gemm_xw(const f16* __restrict__ A, const f16* __restrict__ Bt,
                        const float* __restrict__ bias, f16* __restrict__ C)
{
    __shared__ f16 sA[128 * 32];
    __shared__ f16 sB[128 * 32];
    const int tid = threadIdx.x;
    const int m0 = blockIdx.y * 128;
    const int n0 = blockIdx.x * 128;
    const int wave = tid >> 6, lane = tid & 63;
    const int wm = wave >> 1, wn = wave & 1;
    const int lrow = lane & 15, quad = lane >> 4;

    float4v acc[4][4];
#pragma unroll
    for (int i = 0; i < 4; i++)
#pragma unroll
        for (int j = 0; j < 4; j++) acc[i][j] = (float4v){0.f, 0.f, 0.f, 0.f};

    const int srow = tid >> 2;        // 0..63
    const int sk8 = (tid & 3) * 8;    // 0,8,16,24

    for (int k0 = 0; k0 < 512; k0 += 32) {
#pragma unroll
        for (int rr = 0; rr < 128; rr += 64) {
            const int row = rr + srow;
            *(uint4*)&sA[row * 32 + sk8] = *(const uint4*)&A[(long)(m0 + row) * 512 + k0 + sk8];
            *(uint4*)&sB[row * 32 + sk8] = *(const uint4*)&Bt[(long)(n0 + row) * 512 + k0 + sk8];
        }
        __syncthreads();
        half8 af[4], bf[4];
#pragma unroll
        for (int mi = 0; mi < 4; mi++)
            af[mi] = *(half8*)&sA[(wm * 64 + mi * 16 + lrow) * 32 + quad * 8];
#pragma unroll
        for (int ni = 0; ni < 4; ni++)
            bf[ni] = *(half8*)&sB[(wn * 64 + ni * 16 + lrow) * 32 + quad * 8];
#pragma unroll
        for (int mi = 0; mi < 4; mi++)
#pragma unroll
            for (int ni = 0; ni < 4; ni++)
                acc[mi][ni] = __builtin_amdgcn_mfma_f32_16x16x32_f16(af[mi], bf[ni], acc[mi][ni], 0, 0, 0);
        __syncthreads();
    }
#pragma unroll
    for (int mi = 0; mi < 4; mi++)
#pragma unroll
        for (int ni = 0; ni < 4; ni++)
#pragma unroll
            for (int r = 0; r < 4; r++) {
                int m = m0 + wm * 64 + mi * 16 + quad * 4 + r;
                int n = n0 + wn * 64 + ni * 16 + lrow;
                C[(long)m * NG + n] = (f16)(acc[mi][ni][r] + bias[n]);
            }
}

// ---------------- phase 3: out[b][t][n] = relu(hs @ Wo + bo) (f32 out, row remap) ----------------
__launch_bounds__(256)
__global__ void gemm_hw(const f16* __restrict__ A, const f16* __restrict__ Bt,
                        const float* __restrict__ bias, float* __restrict__ out)
{
    __shared__ f16 sA[128 * 32];
    __shared__ f16 sB[128 * 32];
    const int tid = threadIdx.x;
    const int m0 = blockIdx.y * 128;
    const int n0 = blockIdx.x * 128;
    const int wave = tid >> 6, lane = tid & 63;
    const int wm = wave >> 1, wn = wave & 1;
    const int lrow = lane & 15, quad = lane >> 4;

    float4v acc[4][4];
#pragma unroll
    for (int i = 0; i < 4; i++)
#pragma unroll
        for (int j = 0; j < 4; j++) acc[i][j] = (float4v){0.f, 0.f, 0.f, 0.f};

    const int srow = tid >> 2;
    const int sk8 = (tid & 3) * 8;

    for (int k0 = 0; k0 < 512; k0 += 32) {
#pragma unroll
        for (int rr = 0; rr < 128; rr += 64) {
            const int row = rr + srow;
            *(uint4*)&sA[row * 32 + sk8] = *(const uint4*)&A[(long)(m0 + row) * 512 + k0 + sk8];
            *(uint4*)&sB[row * 32 + sk8] = *(const uint4*)&Bt[(long)(n0 + row) * 512 + k0 + sk8];
        }
        __syncthreads();
        half8 af[4], bf[4];
#pragma unroll
        for (int mi = 0; mi < 4; mi++)
            af[mi] = *(half8*)&sA[(wm * 64 + mi * 16 + lrow) * 32 + quad * 8];
#pragma unroll
        for (int ni = 0; ni < 4; ni++)
            bf[ni] = *(half8*)&sB[(wn * 64 + ni * 16 + lrow) * 32 + quad * 8];
#pragma unroll
        for (int mi = 0; mi < 4; mi++)
#pragma unroll
            for (int ni = 0; ni < 4; ni++)
                acc[mi][ni] = __builtin_amdgcn_mfma_f32_16x16x32_f16(af[mi], bf[ni], acc[mi][ni], 0, 0, 0);
        __syncthreads();
    }
#pragma unroll
    for (int mi = 0; mi < 4; mi++)
#pragma unroll
        for (int ni = 0; ni < 4; ni++)
#pragma unroll
            for (int r = 0; r < 4; r++) {
                int m = m0 + wm * 64 + mi * 16 + quad * 4 + r;   // m = t*B + b
                int n = n0 + wn * 64 + ni * 16 + lrow;
                float v = acc[mi][ni][r] + bias[n];
                v = fmaxf(v, 0.f);
                int t = m >> 5, b = m & 31;
                out[(long)b * (T_ * (long)N_) + (long)t * N_ + n] = v;
            }
}

// ---------------- phase 2: the recurrence ----------------
// 32 groups (one per batch) x 8 blocks x 512 threads. Each thread holds half a
// U column in registers. Cross-block handoff of h uses ONLY relaxed agent-scope
// atomics (lower to global ops with sc1: cache-bypassing, NO buffer_inv/wbl2).
// Release ordering = wave-local s_waitcnt vmcnt(0) between h-stores and flag-add
// (both execute in wave 0, so program order + vmcnt drain suffices).
__launch_bounds__(512, 2)
__global__ void lstm_rec(const f16* __restrict__ Ut,      // [2048 cols][512 rows] f16
                         const f16* __restrict__ xpre,    // [B][T][2048] f16
                         unsigned* __restrict__ hg32,     // [2][32][256] u32 (double buffer, packed f16x2)
                         unsigned* __restrict__ hs32,     // [T][B][256] u32 (packed f16x2)
                         unsigned* __restrict__ flags)    // [32 * 32] (stride 32 -> 128B apart)
{
    const int tid = threadIdx.x;
    const int bb = blockIdx.x & 31;   // batch
    const int s  = blockIdx.x >> 5;   // slice 0..7 (blocks of a group 32 apart -> same XCD)
    const int c    = tid & 255;       // column within block: c = g*64 + e
    const int half = tid >> 8;        // which half of the 512-row column
    const int g = c >> 6, e = c & 63;
    const int gcol = g * 512 + s * 64 + e;   // global gate-column

    __shared__ __align__(16) unsigned hbuf32[256];   // h_{t-1}: 512 f16 packed
    __shared__ float part[512];
    __shared__ float prelds[256];

    // Load U half-column into registers (statically indexed)
    uint4 u[32];
    const uint4* Ub = (const uint4*)(Ut + (long)gcol * 512) + half * 32;
#pragma unroll
    for (int k = 0; k < 32; k++) u[k] = Ub[k];

    if (tid < 256) hbuf32[tid] = 0u;   // h_{-1} = 0
    float c0 = 0.f, c1 = 0.f;          // valid for tid<32: c-state of cols s*64+2*tid{,+1}
    __syncthreads();

    const f16* xp_base = xpre + (long)bb * T_ * NG + gcol;
    unsigned* flag = flags + bb * 32;

    for (int t = 0; t < T_; ++t) {
        float xpv = 0.f;
        if (tid < 256) xpv = (float)xp_base[(long)t * NG];  // independent of h; hides latency

        // dot: pre-activation partial for column gcol over this thread's half rows
        float a0 = 0.f, a1 = 0.f, a2 = 0.f, a3 = 0.f;
        const uint4* hb = ((const uint4*)hbuf32) + half * 32;
#pragma unroll
        for (int k = 0; k < 32; k++) {
            uint4 hv = hb[k];           // broadcast read (all lanes same addr)
            a0 = fdot2(hv.x, u[k].x, a0);
            a1 = fdot2(hv.y, u[k].y, a1);
            a2 = fdot2(hv.z, u[k].z, a2);
            a3 = fdot2(hv.w, u[k].w, a3);
        }
        part[half * 256 + c] = (a0 + a1) + (a2 + a3);
        __syncthreads();

        if (tid < 256) prelds[tid] = part[tid] + part[256 + tid] + xpv;
        __syncthreads();

        const int buf = (t + 1) & 1;
        if (tid < 64) {
            if (tid < 32) {
                const int c2 = 2 * tid;
                float pi0 = prelds[c2],       pi1 = prelds[c2 + 1];
                float pf0 = prelds[64 + c2],  pf1 = prelds[64 + c2 + 1];
                float pg0 = prelds[128 + c2], pg1 = prelds[128 + c2 + 1];
                float pc0 = prelds[192 + c2], pc1 = prelds[192 + c2 + 1];
                float gi0 = 1.f / (1.f + __expf(-pi0)), gi1 = 1.f / (1.f + __expf(-pi1));
                float gf0 = 1.f / (1.f + __expf(-pf0)), gf1 = 1.f / (1.f + __expf(-pf1));
                float gg0 = 1.f / (1.f + __expf(-pg0)), gg1 = 1.f / (1.f + __expf(-pg1));
                float ct0 = tanhf(pc0), ct1 = tanhf(pc1);
                c0 = gf0 * c0 + gi0 * ct0;
                c1 = gf1 * c1 + gi1 * ct1;
                float h0 = gg0 * tanhf(c0);
                float h1 = gg1 * tanhf(c1);
                union { f16 h[2]; unsigned u; } pk;
                pk.h[0] = (f16)h0; pk.h[1] = (f16)h1;
                // cross-block handoff: relaxed agent atomic store (sc1, no cache flush)
                __hip_atomic_store(&hg32[buf * 8192 + bb * 256 + s * 32 + tid], pk.u,
                                   __ATOMIC_RELAXED, __HIP_MEMORY_SCOPE_AGENT);
                // history for gemm_hw: normal cached store
                hs32[((long)t * B_ + bb) * 256 + s * 32 + tid] = pk.u;
            }
            // wave 0: drain our stores to the coherence point, THEN bump the flag.
            asm volatile("s_waitcnt vmcnt(0)" ::: "memory");
            if (tid == 0) {
                __hip_atomic_fetch_add(flag, 1u, __ATOMIC_RELAXED, __HIP_MEMORY_SCOPE_AGENT);
                const unsigned target = 8u * (unsigned)(t + 1);
                while (__hip_atomic_load(flag, __ATOMIC_RELAXED, __HIP_MEMORY_SCOPE_AGENT) < target)
                    __builtin_amdgcn_s_sleep(2);
            }
        }
        __syncthreads();

        // pull peers' h via relaxed agent atomic loads (sc1: bypass stale caches)
        if (tid < 256)
            hbuf32[tid] = __hip_atomic_load(&hg32[buf * 8192 + bb * 256 + tid],
                                            __ATOMIC_RELAXED, __HIP_MEMORY_SCOPE_AGENT);
        __syncthreads();
    }
}

// ---------------- launch ----------------
extern "C" void kernel_launch(void* const* d_in, const int* in_sizes, int n_in,
                              void* d_out, int out_size, void* d_ws, size_t ws_size,
                              hipStream_t stream)
{
    const float* x  = (const float*)d_in[0];
    const float* Wi = (const float*)d_in[1];
    const float* Ui = (const float*)d_in[2];
    const float* Wf = (const float*)d_in[3];
    const float* Uf = (const float*)d_in[4];
    const float* Wg = (const float*)d_in[5];
    const float* Ug = (const float*)d_in[6];
    const float* Wc = (const float*)d_in[7];
    const float* Uc = (const float*)d_in[8];
    const float* Wo = (const float*)d_in[9];
    const float* bi = (const float*)d_in[10];
    const float* bf = (const float*)d_in[11];
    const float* bg = (const float*)d_in[12];
    const float* bc = (const float*)d_in[13];
    const float* bo = (const float*)d_in[14];

    char* ws = (char*)d_ws;
    f16*      x16   = (f16*)(ws + 0L);            // 64 MB
    f16*      xpre  = (f16*)(ws + 67108864L);     // 256 MB
    f16*      hs    = (f16*)(ws + 335544320L);    // 64 MB
    f16*      wt    = (f16*)(ws + 402653184L);    // 2 MB
    f16*      ut    = (f16*)(ws + 404750336L);    // 2 MB
    f16*      wot   = (f16*)(ws + 406847488L);    // 0.5 MB
    float*    bias  = (float*)(ws + 407371776L);  // 8 KB
    unsigned* hg    = (unsigned*)(ws + 407379968L); // 64 KB
    unsigned* flags = (unsigned*)(ws + 407445504L); // 4 KB

    prep_cast<<<dim3(32768), dim3(256), 0, stream>>>(x, x16);
    prep_w<<<dim3(1024, 10), dim3(256), 0, stream>>>(Wi, Ui, Wf, Uf, Wg, Ug, Wc, Uc, Wo,
                                                     bi, bf, bg, bc, wt, ut, wot, bias, flags);
    gemm_xw<<<dim3(16, 512), dim3(256), 0, stream>>>(x16, wt, bias, xpre);
    lstm_rec<<<dim3(256), dim3(512), 0, stream>>>(ut, xpre, hg, (unsigned*)hs, flags);
    gemm_hw<<<dim3(4, 512), dim3(256), 0, stream>>>(hs, wot, bo, (float*)d_out);
}

// Round 3
// 4715.591 us; speedup vs baseline: 17.2042x; 1.3914x over previous
//
#include <hip/hip_runtime.h>
#include <stdint.h>

// Problem constants
#define B_ 32
#define T_ 2048
#define D_ 512
#define N_ 512
#define NG 2048   // 4 gates * N

typedef _Float16 f16;
typedef _Float16 half2v __attribute__((ext_vector_type(2)));
typedef _Float16 half8  __attribute__((ext_vector_type(8)));
typedef float    float4v __attribute__((ext_vector_type(4)));
typedef unsigned long long u64;

union U32H2 { unsigned u; half2v h; };

static __device__ __forceinline__ float fdot2(unsigned a, unsigned b, float c) {
#if __has_builtin(__builtin_amdgcn_fdot2)
    U32H2 ua; ua.u = a; U32H2 ub; ub.u = b;
    return __builtin_amdgcn_fdot2(ua.h, ub.h, c, false);
#else
    U32H2 ua; ua.u = a; U32H2 ub; ub.u = b;
    c += (float)ua.h[0] * (float)ub.h[0];
    c += (float)ua.h[1] * (float)ub.h[1];
    return c;
#endif
}

// ---------------- prep: cast x (f32) -> f16 ----------------
__global__ void prep_cast(const float* __restrict__ x, f16* __restrict__ x16) {
    long i = ((long)blockIdx.x * 256 + threadIdx.x) * 4;
    float4 v = *(const float4*)(x + i);
    union { f16 h[4]; uint2 u; } pk;
    pk.h[0] = (f16)v.x; pk.h[1] = (f16)v.y; pk.h[2] = (f16)v.z; pk.h[3] = (f16)v.w;
    *(uint2*)(x16 + i) = pk.u;
}

// ---------------- prep: transpose+cast weights, biases ----------------
__global__ void prep_w(const float* __restrict__ Wi, const float* __restrict__ Ui,
                       const float* __restrict__ Wf, const float* __restrict__ Uf,
                       const float* __restrict__ Wg, const float* __restrict__ Ug,
                       const float* __restrict__ Wc, const float* __restrict__ Uc,
                       const float* __restrict__ Wo,
                       const float* __restrict__ bi, const float* __restrict__ bff,
                       const float* __restrict__ bg, const float* __restrict__ bc,
                       f16* __restrict__ wt, f16* __restrict__ ut,
                       f16* __restrict__ wot, float* __restrict__ bias)
{
    const int y = blockIdx.y;
    const int e = blockIdx.x * 256 + threadIdx.x;   // 0..262143
    if (y < 4) {
        const float* src = (y == 0) ? Wi : (y == 1) ? Wf : (y == 2) ? Wg : Wc;
        int col = e >> 9, d = e & 511;
        wt[(long)y * 512 * 512 + e] = (f16)src[(long)d * 512 + col];   // wt[(g*512+col)][d]
    } else if (y < 8) {
        const float* src = (y == 4) ? Ui : (y == 5) ? Uf : (y == 6) ? Ug : Uc;
        int col = e >> 9, d = e & 511;
        ut[(long)(y - 4) * 512 * 512 + e] = (f16)src[(long)d * 512 + col];
    } else if (y == 8) {
        int col = e >> 9, d = e & 511;
        wot[e] = (f16)Wo[(long)d * 512 + col];
    } else {
        if (e < 2048) {
            const float* bsrc = (e < 512) ? bi : (e < 1024) ? bff : (e < 1536) ? bg : bc;
            bias[e] = bsrc[e & 511];
        }
    }
}

// ---------------- phase 1: xpre[b][t][2048] = x @ [Wi|Wf|Wg|Wc] + bias (f16 out) ----------------
__launch_bounds__(256)
__global__ void gemm_xw(const f16* __restrict__ A, const f16* __restrict__ Bt,
                        const float* __restrict__ bias, f16* __restrict__ C)
{
    __shared__ f16 sA[128 * 32];
    __shared__ f16 sB[128 * 32];
    const int tid = threadIdx.x;
    const int m0 = blockIdx.y * 128;
    const int n0 = blockIdx.x * 128;
    const int wave = tid >> 6, lane = tid & 63;
    const int wm = wave >> 1, wn = wave & 1;
    const int lrow = lane & 15, quad = lane >> 4;

    float4v acc[4][4];
#pragma unroll
    for (int i = 0; i < 4; i++)
#pragma unroll
        for (int j = 0; j < 4; j++) acc[i][j] = (float4v){0.f, 0.f, 0.f, 0.f};

    const int srow = tid >> 2;        // 0..63
    const int sk8 = (tid & 3) * 8;    // 0,8,16,24

    for (int k0 = 0; k0 < 512; k0 += 32) {
#pragma unroll
        for (int rr = 0; rr < 128; rr += 64) {
            const int row = rr + srow;
            *(uint4*)&sA[row * 32 + sk8] = *(const uint4*)&A[(long)(m0 + row) * 512 + k0 + sk8];
            *(uint4*)&sB[row * 32 + sk8] = *(const uint4*)&Bt[(long)(n0 + row) * 512 + k0 + sk8];
        }
        __syncthreads();
        half8 af[4], bf[4];
#pragma unroll
        for (int mi = 0; mi < 4; mi++)
            af[mi] = *(half8*)&sA[(wm * 64 + mi * 16 + lrow) * 32 + quad * 8];
#pragma unroll
        for (int ni = 0; ni < 4; ni++)
            bf[ni] = *(half8*)&sB[(wn * 64 + ni * 16 + lrow) * 32 + quad * 8];
#pragma unroll
        for (int mi = 0; mi < 4; mi++)
#pragma unroll
            for (int ni = 0; ni < 4; ni++)
                acc[mi][ni] = __builtin_amdgcn_mfma_f32_16x16x32_f16(af[mi], bf[ni], acc[mi][ni], 0, 0, 0);
        __syncthreads();
    }
#pragma unroll
    for (int mi = 0; mi < 4; mi++)
#pragma unroll
        for (int ni = 0; ni < 4; ni++)
#pragma unroll
            for (int r = 0; r < 4; r++) {
                int m = m0 + wm * 64 + mi * 16 + quad * 4 + r;
                int n = n0 + wn * 64 + ni * 16 + lrow;
                C[(long)m * NG + n] = (f16)(acc[mi][ni][r] + bias[n]);
            }
}

// ---------------- phase 3: out[b][t][n] = relu(hs @ Wo + bo) (f32 out, row remap) ----------------
__launch_bounds__(256)
__global__ void gemm_hw(const f16* __restrict__ A, const f16* __restrict__ Bt,
                        const float* __restrict__ bias, float* __restrict__ out)
{
    __shared__ f16 sA[128 * 32];
    __shared__ f16 sB[128 * 32];
    const int tid = threadIdx.x;
    const int m0 = blockIdx.y * 128;
    const int n0 = blockIdx.x * 128;
    const int wave = tid >> 6, lane = tid & 63;
    const int wm = wave >> 1, wn = wave & 1;
    const int lrow = lane & 15, quad = lane >> 4;

    float4v acc[4][4];
#pragma unroll
    for (int i = 0; i < 4; i++)
#pragma unroll
        for (int j = 0; j < 4; j++) acc[i][j] = (float4v){0.f, 0.f, 0.f, 0.f};

    const int srow = tid >> 2;
    const int sk8 = (tid & 3) * 8;

    for (int k0 = 0; k0 < 512; k0 += 32) {
#pragma unroll
        for (int rr = 0; rr < 128; rr += 64) {
            const int row = rr + srow;
            *(uint4*)&sA[row * 32 + sk8] = *(const uint4*)&A[(long)(m0 + row) * 512 + k0 + sk8];
            *(uint4*)&sB[row * 32 + sk8] = *(const uint4*)&Bt[(long)(n0 + row) * 512 + k0 + sk8];
        }
        __syncthreads();
        half8 af[4], bf[4];
#pragma unroll
        for (int mi = 0; mi < 4; mi++)
            af[mi] = *(half8*)&sA[(wm * 64 + mi * 16 + lrow) * 32 + quad * 8];
#pragma unroll
        for (int ni = 0; ni < 4; ni++)
            bf[ni] = *(half8*)&sB[(wn * 64 + ni * 16 + lrow) * 32 + quad * 8];
#pragma unroll
        for (int mi = 0; mi < 4; mi++)
#pragma unroll
            for (int ni = 0; ni < 4; ni++)
                acc[mi][ni] = __builtin_amdgcn_mfma_f32_16x16x32_f16(af[mi], bf[ni], acc[mi][ni], 0, 0, 0);
        __syncthreads();
    }
#pragma unroll
    for (int mi = 0; mi < 4; mi++)
#pragma unroll
        for (int ni = 0; ni < 4; ni++)
#pragma unroll
            for (int r = 0; r < 4; r++) {
                int m = m0 + wm * 64 + mi * 16 + quad * 4 + r;   // m = t*B + b
                int n = n0 + wn * 64 + ni * 16 + lrow;
                float v = acc[mi][ni][r] + bias[n];
                v = fmaxf(v, 0.f);
                int t = m >> 5, b = m & 31;
                out[(long)b * (T_ * (long)N_) + (long)t * N_ + n] = v;
            }
}

// ---------------- phase 2: the recurrence ----------------
// 32 groups (one per batch) x 8 blocks x 512 threads. Each thread holds half a
// U column in registers (lane-pair mapping: even lane = rows 0..255, odd lane =
// rows 256..511 of column tid>>1's gate-column). Cross-block handoff: ONE
// tagged u64 per h-pair -- (tag=t+1)<<32 | f16x2 -- stored/loaded with relaxed
// agent-scope atomics. Consumers poll the data word itself: single global
// round-trip on the critical path, no flag, no fence, no cache maintenance.
// Safety of parity double-buffer: producer overwrites slot parity p (h^t over
// h^{t-2}) only after its block observed tag t on ALL slots, which requires
// every peer block to have passed the barrier following its h^{t-2} reads.
__launch_bounds__(512, 2)
__global__ void lstm_rec(const f16* __restrict__ Ut,      // [2048 cols][512 rows] f16
                         const f16* __restrict__ xpre,    // [B][T][2048] f16
                         u64* __restrict__ hg64,          // [2][32][256] tagged h pairs
                         unsigned* __restrict__ hs32,     // [T][B][256] u32 (packed f16x2)
                         int unused)
{
    const int tid = threadIdx.x;
    const int bb = blockIdx.x & 31;   // batch
    const int s  = blockIdx.x >> 5;   // slice 0..7 (blocks of a group 32 apart -> same XCD)
    const int col  = tid >> 1;        // 0..255 : column within block = g*64 + e
    const int half = tid & 1;         // which half of the 512-row column
    const int g = col >> 6, e = col & 63;
    const int gcol = g * 512 + s * 64 + e;   // global gate-column

    __shared__ __align__(16) unsigned hbuf32[256];   // h_{t-1}: 512 f16 packed
    __shared__ float prelds[256];

    // Load U half-column into registers (statically indexed)
    uint4 u[32];
    const uint4* Ub = (const uint4*)(Ut + (long)gcol * 512) + half * 32;
#pragma unroll
    for (int k = 0; k < 32; k++) u[k] = Ub[k];

    if (tid < 256) hbuf32[tid] = 0u;   // h_{-1} = 0
    float c0 = 0.f, c1 = 0.f;          // valid for tid<32: c-state of cols s*64+2*tid{,+1}
    __syncthreads();

    const f16* xp_base = xpre + (long)bb * T_ * NG + gcol;

    for (int t = 0; t < T_; ++t) {
        // xpre value for this column (needed by even lanes only); issued before
        // the poll so its latency overlaps the wait.
        float xpv = 0.f;
        if (half == 0) xpv = (float)xp_base[(long)t * NG];

        // ---- acquire h_{t-1} : poll tagged data words directly ----
        if (t > 0 && tid < 256) {
            const u64* slot = hg64 + (size_t)(t & 1) * 8192 + bb * 256 + tid;
            const unsigned tag = (unsigned)t;
            u64 v;
            while ((unsigned)((v = __hip_atomic_load(slot, __ATOMIC_RELAXED,
                                                     __HIP_MEMORY_SCOPE_AGENT)) >> 32) != tag)
                __builtin_amdgcn_s_sleep(1);
            hbuf32[tid] = (unsigned)v;
        }
        __syncthreads();

        // ---- dot: partial pre-activation for column gcol over this half ----
        float a0 = 0.f, a1 = 0.f, a2 = 0.f, a3 = 0.f;
        const uint4* hb = ((const uint4*)hbuf32) + half * 32;
#pragma unroll
        for (int k = 0; k < 32; k++) {
            uint4 hv = hb[k];           // 2-address broadcast (2-way bank alias: free)
            a0 = fdot2(hv.x, u[k].x, a0);
            a1 = fdot2(hv.y, u[k].y, a1);
            a2 = fdot2(hv.z, u[k].z, a2);
            a3 = fdot2(hv.w, u[k].w, a3);
        }
        float sum = (a0 + a1) + (a2 + a3);
        sum += __shfl_xor(sum, 1);      // combine the two row-halves (lane pair)
        if (half == 0) prelds[col] = sum + xpv;
        __syncthreads();

        // ---- gates + state update + tagged release store ----
        if (tid < 32) {
            const int c2 = 2 * tid;
            float pi0 = prelds[c2],       pi1 = prelds[c2 + 1];
            float pf0 = prelds[64 + c2],  pf1 = prelds[64 + c2 + 1];
            float pg0 = prelds[128 + c2], pg1 = prelds[128 + c2 + 1];
            float pc0 = prelds[192 + c2], pc1 = prelds[192 + c2 + 1];
            float gi0 = 1.f / (1.f + __expf(-pi0)), gi1 = 1.f / (1.f + __expf(-pi1));
            float gf0 = 1.f / (1.f + __expf(-pf0)), gf1 = 1.f / (1.f + __expf(-pf1));
            float gg0 = 1.f / (1.f + __expf(-pg0)), gg1 = 1.f / (1.f + __expf(-pg1));
            float ct0 = tanhf(pc0), ct1 = tanhf(pc1);
            c0 = gf0 * c0 + gi0 * ct0;
            c1 = gf1 * c1 + gi1 * ct1;
            float h0 = gg0 * tanhf(c0);
            float h1 = gg1 * tanhf(c1);
            union { f16 h[2]; unsigned u; } pk;
            pk.h[0] = (f16)h0; pk.h[1] = (f16)h1;
            u64 pv = ((u64)(unsigned)(t + 1) << 32) | (u64)pk.u;
            __hip_atomic_store(hg64 + (size_t)((t + 1) & 1) * 8192 + bb * 256 + s * 32 + tid,
                               pv, __ATOMIC_RELAXED, __HIP_MEMORY_SCOPE_AGENT);
            // history for gemm_hw: normal cached store (not on critical path)
            hs32[((long)t * B_ + bb) * 256 + s * 32 + tid] = pk.u;
        }
        // no trailing barrier: next iteration's poll + barrier provide ordering
    }
}

// ---------------- launch ----------------
extern "C" void kernel_launch(void* const* d_in, const int* in_sizes, int n_in,
                              void* d_out, int out_size, void* d_ws, size_t ws_size,
                              hipStream_t stream)
{
    const float* x  = (const float*)d_in[0];
    const float* Wi = (const float*)d_in[1];
    const float* Ui = (const float*)d_in[2];
    const float* Wf = (const float*)d_in[3];
    const float* Uf = (const float*)d_in[4];
    const float* Wg = (const float*)d_in[5];
    const float* Ug = (const float*)d_in[6];
    const float* Wc = (const float*)d_in[7];
    const float* Uc = (const float*)d_in[8];
    const float* Wo = (const float*)d_in[9];
    const float* bi = (const float*)d_in[10];
    const float* bf = (const float*)d_in[11];
    const float* bg = (const float*)d_in[12];
    const float* bc = (const float*)d_in[13];
    const float* bo = (const float*)d_in[14];

    char* ws = (char*)d_ws;
    f16*      x16   = (f16*)(ws + 0L);            // 64 MB
    f16*      xpre  = (f16*)(ws + 67108864L);     // 256 MB
    f16*      hs    = (f16*)(ws + 335544320L);    // 64 MB
    f16*      wt    = (f16*)(ws + 402653184L);    // 2 MB
    f16*      ut    = (f16*)(ws + 404750336L);    // 2 MB
    f16*      wot   = (f16*)(ws + 406847488L);    // 0.5 MB
    float*    bias  = (float*)(ws + 407371776L);  // 8 KB
    u64*      hg64  = (u64*)(ws + 407379968L);    // 128 KB tagged h exchange
    // hg64 is re-poisoned to 0xAA each call -> tag 0xAAAAAAAA never matches a
    // real t in [1,2048], so stale data cannot satisfy a poll.

    prep_cast<<<dim3(32768), dim3(256), 0, stream>>>(x, x16);
    prep_w<<<dim3(1024, 10), dim3(256), 0, stream>>>(Wi, Ui, Wf, Uf, Wg, Ug, Wc, Uc, Wo,
                                                     bi, bf, bg, bc, wt, ut, wot, bias);
    gemm_xw<<<dim3(16, 512), dim3(256), 0, stream>>>(x16, wt, bias, xpre);
    lstm_rec<<<dim3(256), dim3(512), 0, stream>>>(ut, xpre, hg64, (unsigned*)hs, 0);
    gemm_hw<<<dim3(4, 512), dim3(256), 0, stream>>>(hs, wot, bo, (float*)d_out);
}